// Round 5
// baseline (249.414 us; speedup 1.0000x reference)
//
#include <hip/hip_runtime.h>
#include <math.h>

// Problem constants
#define B_ 4
#define S_ 2048
#define E_ 512
#define H_ 8
#define D_ 64

typedef short bf16x8 __attribute__((ext_vector_type(8)));
typedef float f32x4 __attribute__((ext_vector_type(4)));

__device__ inline short f2bf(float f) {  // fp32 -> bf16 bits, RNE
  union { float f; unsigned u; } v; v.f = f;
  unsigned r = v.u + 0x7FFF + ((v.u >> 16) & 1);
  return (short)(r >> 16);
}
__device__ inline short f2bf_fast(float f) {  // round-half-up (P matrix only)
  union { float f; unsigned u; } v; v.f = f;
  return (short)((v.u + 0x8000u) >> 16);
}
__device__ inline float bf2f(short s) {
  union { unsigned u; float f; } v; v.u = ((unsigned)(unsigned short)s) << 16;
  return v.f;
}
// raw v_exp_f32: 2^x in one instruction (libm exp2f is ~10 instrs of
// edge-case scaffolding; our inputs are finite, very-negative -> 0 is the
// desired mask behavior). ISA ref cdna4_isa.md §3.
__device__ __forceinline__ float exp2_hw(float x) {
  float r; asm("v_exp_f32 %0, %1" : "=v"(r) : "v"(x)); return r;
}

// Async global->LDS, 16B per lane. HW writes wave-uniform LDS base + lane*16;
// every wave's per-lane pointers here are exactly base+lane*16 (flat unpadded
// layout, slot = tid*16B; uniform buffer offset preserves the property).
__device__ __forceinline__ void gload16(const short* g, short* l) {
  __builtin_amdgcn_global_load_lds(
      (__attribute__((address_space(1))) void*)g,
      (__attribute__((address_space(3))) void*)l, 16, 0, 0);
}

// ---------------------------------------------------------------------------
// fused fp32->bf16 convert for X, W_in, W_out in ONE launch (block ranges)
// ---------------------------------------------------------------------------
__global__ __launch_bounds__(256) void cvt_all(
    const float* __restrict__ x, const float* __restrict__ win,
    const float* __restrict__ wout, short* __restrict__ xb,
    short* __restrict__ winb, short* __restrict__ woutb) {
  int bid = blockIdx.x;
  const float* src; short* dst; int i;
  if (bid < 4096)      { src = x;    dst = xb;    i = bid * 256 + threadIdx.x; }
  else if (bid < 4864) { src = win;  dst = winb;  i = (bid - 4096) * 256 + threadIdx.x; }
  else                 { src = wout; dst = woutb; i = (bid - 4864) * 256 + threadIdx.x; }
  float4 f = ((const float4*)src)[i];
  short4 o;
  o.x = f2bf(f.x); o.y = f2bf(f.y); o.z = f2bf(f.z); o.w = f2bf(f.w);
  ((short4*)dst)[i] = o;
}

// ---------------------------------------------------------------------------
// MFMA GEMM qkv (r4 structure, unchanged): 128x64 tile, BK=32, 4 waves,
// async global_load_lds staging, LDS dbuf, ONE barrier/K-step, 1536 blocks
// = 6/CU. Epilogue fuses RoPE; q,k [bh][s][d]; V TRANSPOSED [bh][d][s].
// ---------------------------------------------------------------------------
__global__ __launch_bounds__(256, 6) void gemm_qkv_mfma(
    const short* __restrict__ Xb,    // [8192][512] bf16
    const short* __restrict__ Wb,    // [1536][512] bf16
    short* __restrict__ qb, short* __restrict__ kb, short* __restrict__ vbT) {
  __shared__ __align__(16) short As[2 * 128 * 32];   // 16 KB
  __shared__ __align__(16) short Bs[2 * 64 * 32];    //  8 KB
  const int tid = threadIdx.x;
  const int w = tid >> 6, lane = tid & 63;
  const int l15 = lane & 15, quad = lane >> 4;
  const int wm = w & 1, wn = w >> 1;
  const int m0 = blockIdx.x * 128;
  const int n0 = blockIdx.y * 64;

  const int srow = tid >> 2, sch = (tid & 3) * 8;
  const short* gA0 = Xb + (size_t)(m0 + srow) * E_ + sch;
  const short* gA1 = Xb + (size_t)(m0 + srow + 64) * E_ + sch;
  const short* gB0 = Wb + (size_t)(n0 + srow) * E_ + sch;

  f32x4 acc[4][2];
  for (int mt = 0; mt < 4; ++mt)
    for (int nt = 0; nt < 2; ++nt) acc[mt][nt] = (f32x4){0.f, 0.f, 0.f, 0.f};

  gload16(gA0, &As[tid * 8]);
  gload16(gA1, &As[2048 + tid * 8]);
  gload16(gB0, &Bs[tid * 8]);
  gA0 += 32; gA1 += 32; gB0 += 32;
  __syncthreads();

  int cur = 0;
  for (int t = 0; t < 16; ++t) {
    if (t < 15) {
      const int nbA = (cur ^ 1) * 4096, nbB = (cur ^ 1) * 2048;
      gload16(gA0, &As[nbA + tid * 8]);
      gload16(gA1, &As[nbA + 2048 + tid * 8]);
      gload16(gB0, &Bs[nbB + tid * 8]);
      gA0 += 32; gA1 += 32; gB0 += 32;
    }
    const int cbA = cur * 4096, cbB = cur * 2048;
    bf16x8 a[4], bfr[2];
#pragma unroll
    for (int mt = 0; mt < 4; ++mt)
      a[mt] = *(const bf16x8*)&As[cbA + (wm * 64 + mt * 16 + l15) * 32 + quad * 8];
#pragma unroll
    for (int nt = 0; nt < 2; ++nt)
      bfr[nt] = *(const bf16x8*)&Bs[cbB + (wn * 32 + nt * 16 + l15) * 32 + quad * 8];
#pragma unroll
    for (int mt = 0; mt < 4; ++mt)
#pragma unroll
      for (int nt = 0; nt < 2; ++nt)
        acc[mt][nt] = __builtin_amdgcn_mfma_f32_16x16x32_bf16(a[mt], bfr[nt], acc[mt][nt], 0, 0, 0);
    __syncthreads();
    cur ^= 1;
  }

  const int t3 = n0 >> 9;                // uniform per block: 0=q 1=k 2=v
  for (int nt = 0; nt < 2; ++nt) {
    const int n = n0 + wn * 32 + nt * 16 + l15;
    const int h = (n >> 6) & 7;
    const int d = n & 63;
    const bool dorope = (t3 < 2) && (d < 32);
    const float sgn = (d & 1) ? 1.f : -1.f;
    const float fr = dorope ? exp2f((float)(d >> 1) * -0.8304820237f) : 0.f;
    for (int mt = 0; mt < 4; ++mt) {
      for (int i = 0; i < 4; ++i) {
        const int m = m0 + wm * 64 + mt * 16 + quad * 4 + i;
        const int b = m >> 11, s = m & (S_ - 1);
        float val = acc[mt][nt][i];
        float pv = __shfl_xor(val, 1, 64);
        float outv = val;
        if (dorope) {
          float ang = (float)s * fr;
          float sn, cs;
          sincosf(ang, &sn, &cs);
          outv = val * cs + pv * sgn * sn;
        }
        if (t3 == 2)
          vbT[((size_t)(b * 8 + h) * D_ + d) * S_ + s] = f2bf(outv);
        else {
          short* dst = (t3 == 0) ? qb : kb;
          dst[(((size_t)(b * 8 + h)) * S_ + s) * D_ + d] = f2bf(outv);
        }
      }
    }
  }
}

// ---------------------------------------------------------------------------
// gemm_out: out = ob @ Woutb^T, fp32 output (r4 structure, unchanged).
// ---------------------------------------------------------------------------
__global__ __launch_bounds__(256) void gemm_out_mfma(
    const short* __restrict__ Ab, const short* __restrict__ Wb,
    float* __restrict__ out) {
  __shared__ __align__(16) short As[2 * 128 * 32];
  __shared__ __align__(16) short Bs[2 * 64 * 32];
  const int tid = threadIdx.x;
  const int w = tid >> 6, lane = tid & 63;
  const int l15 = lane & 15, quad = lane >> 4;
  const int wm = w & 1, wn = w >> 1;
  const int m0 = blockIdx.x * 128;
  const int n0 = blockIdx.y * 64;

  const int srow = tid >> 2, sch = (tid & 3) * 8;
  const short* gA0 = Ab + (size_t)(m0 + srow) * E_ + sch;
  const short* gA1 = Ab + (size_t)(m0 + srow + 64) * E_ + sch;
  const short* gB0 = Wb + (size_t)(n0 + srow) * E_ + sch;

  f32x4 acc[4][2];
  for (int mt = 0; mt < 4; ++mt)
    for (int nt = 0; nt < 2; ++nt) acc[mt][nt] = (f32x4){0.f, 0.f, 0.f, 0.f};

  gload16(gA0, &As[tid * 8]);
  gload16(gA1, &As[2048 + tid * 8]);
  gload16(gB0, &Bs[tid * 8]);
  gA0 += 32; gA1 += 32; gB0 += 32;
  __syncthreads();

  int cur = 0;
  for (int t = 0; t < 16; ++t) {
    if (t < 15) {
      const int nbA = (cur ^ 1) * 4096, nbB = (cur ^ 1) * 2048;
      gload16(gA0, &As[nbA + tid * 8]);
      gload16(gA1, &As[nbA + 2048 + tid * 8]);
      gload16(gB0, &Bs[nbB + tid * 8]);
      gA0 += 32; gA1 += 32; gB0 += 32;
    }
    const int cbA = cur * 4096, cbB = cur * 2048;
    bf16x8 a[4], bfr[2];
#pragma unroll
    for (int mt = 0; mt < 4; ++mt)
      a[mt] = *(const bf16x8*)&As[cbA + (wm * 64 + mt * 16 + l15) * 32 + quad * 8];
#pragma unroll
    for (int nt = 0; nt < 2; ++nt)
      bfr[nt] = *(const bf16x8*)&Bs[cbB + (wn * 32 + nt * 16 + l15) * 32 + quad * 8];
#pragma unroll
    for (int mt = 0; mt < 4; ++mt)
#pragma unroll
      for (int nt = 0; nt < 2; ++nt)
        acc[mt][nt] = __builtin_amdgcn_mfma_f32_16x16x32_bf16(a[mt], bfr[nt], acc[mt][nt], 0, 0, 0);
    __syncthreads();
    cur ^= 1;
  }
  for (int mt = 0; mt < 4; ++mt)
    for (int nt = 0; nt < 2; ++nt) {
      const int n = n0 + wn * 32 + nt * 16 + l15;
      for (int i = 0; i < 4; ++i) {
        const int m = m0 + wm * 64 + mt * 16 + quad * 4 + i;
        out[(size_t)m * E_ + n] = acc[mt][nt][i];
      }
    }
}

// ---------------------------------------------------------------------------
// Flash attention r5: NO K/V LDS staging, NO per-tile barriers.
// r4 counters: VALUBusy 45% / MfmaUtil 15% / 4.87M bank conflicts -> VALU-
// bound with ~400 VALU/tile/wave. Cuts: (1) exp2f -> raw v_exp_f32 (~130
// VALU/tile); (2) K/V fragments read DIRECT from global: per-XCD working
// set = 4bh x 512KB = 2MB < 4MB L2 (bid&7 XCD swizzle), so LDS staging was
// pure overhead (guide attn lesson #7) — removes staging + BOTH barriers;
// (3) kbias LDS -> per-wave reg + 4 bpermutes. Pl P-transpose round-trip is
// wave-private (no barrier) and kept as-is. Waves now fully independent.
// ---------------------------------------------------------------------------
__global__ __launch_bounds__(256, 4) void flash_mfma(
    const short* __restrict__ qb, const short* __restrict__ kb,
    const short* __restrict__ vbT, const int* __restrict__ maskp,
    short* __restrict__ pb0, short* __restrict__ pb1,
    float* __restrict__ lb0, float* __restrict__ lb1,
    short* __restrict__ ob) {
  __shared__ __align__(16) short Pl[4][16][72];
  const int tid = threadIdx.x;
  const int w = tid >> 6, lane = tid & 63;
  const int l15 = lane & 15, quad = lane >> 4;
  const int bid = blockIdx.x;
  const int u = bid & 7, v = bid >> 3;       // u -> XCD under id&7 model
  const int bh = (u << 2) | (v & 3);         // 4 bh per XCD
  const int w2 = v >> 2;                     // 0..31
  const int pair = w2 & 15;                  // q-tile pair id
  const int kh = w2 >> 4;                    // split half: 0 or 1
  const int b = bh >> 3, hd = bh & 7;
  const short* qbase = qb + (size_t)bh * S_ * D_;
  const short* kbase = kb + (size_t)bh * S_ * D_;
  const short* vtb   = vbT + (size_t)bh * D_ * S_;
  short* PB = kh ? pb1 : pb0;
  float* LB = kh ? lb1 : lb0;
  const float c2 = 0.1803368801f;            // 0.125 * log2(e)
  bf16x8 ones;
  for (int j = 0; j < 8; ++j) ones[j] = (short)0x3F80;  // bf16 1.0

  // per-lane fragment base pointers (L2-resident reads)
  const short* kfrag = kbase + l15 * D_ + quad * 8;   // + (t0+16nb)*D_ + 32ks
  const short* vf0 = vtb + (size_t)(l15) * S_ + quad * 8;        // + t0+32ks
  const short* vf1 = vtb + (size_t)(16 + l15) * S_ + quad * 8;
  const short* vf2 = vtb + (size_t)(32 + l15) * S_ + quad * 8;
  const short* vf3 = vtb + (size_t)(48 + l15) * S_ + quad * 8;

  for (int seg = 0; seg < 2; ++seg) {
    const int qt = (seg == 0) ? pair : 31 - pair;
    const int r0 = qt * 64;
    const int mid = (qt + 2) >> 1;           // ceil((qt+1)/2)
    const int lo = kh ? mid : 0;
    const int hi = kh ? (qt + 1) : mid;
    bf16x8 aq[2];
    {
      const short* qrow = qbase + (size_t)(r0 + 16 * w + l15) * D_;
      aq[0] = *(const bf16x8*)&qrow[quad * 8];
      aq[1] = *(const bf16x8*)&qrow[32 + quad * 8];
    }
    f32x4 o[4], lsum;
    for (int no = 0; no < 4; ++no) o[no] = (f32x4){0.f, 0.f, 0.f, 0.f};
    lsum = (f32x4){0.f, 0.f, 0.f, 0.f};

    for (int kt = lo; kt < hi; ++kt) {
      const int t0 = kt * 64;
      // per-wave key bias (replaces kbias LDS + barrier)
      const float kbr = maskp[b * S_ + t0 + lane] ? -23.08312f : -1.0e38f;
      // K fragments direct from L2
      bf16x8 bk[4][2];
#pragma unroll
      for (int nb = 0; nb < 4; ++nb)
#pragma unroll
        for (int ks = 0; ks < 2; ++ks)
          bk[nb][ks] = *(const bf16x8*)(kfrag + (size_t)(t0 + 16 * nb) * D_ + 32 * ks);
      f32x4 sfr[4];
      for (int nb = 0; nb < 4; ++nb) sfr[nb] = (f32x4){0.f, 0.f, 0.f, 0.f};
#pragma unroll
      for (int nb = 0; nb < 4; ++nb)
#pragma unroll
        for (int ks = 0; ks < 2; ++ks)
          sfr[nb] = __builtin_amdgcn_mfma_f32_16x16x32_bf16(aq[ks], bk[nb][ks], sfr[nb], 0, 0, 0);
      // V fragments direct from L2 — issued before softmax so latency hides
      bf16x8 bv[4][2];
#pragma unroll
      for (int ks = 0; ks < 2; ++ks) {
        bv[0][ks] = *(const bf16x8*)(vf0 + t0 + 32 * ks);
        bv[1][ks] = *(const bf16x8*)(vf1 + t0 + 32 * ks);
        bv[2][ks] = *(const bf16x8*)(vf2 + t0 + 32 * ks);
        bv[3][ks] = *(const bf16x8*)(vf3 + t0 + 32 * ks);
      }
      if (kt < qt) {                         // interior tiles: no causal test
#pragma unroll
        for (int nb = 0; nb < 4; ++nb) {
          const float bb = __shfl(kbr, l15 + 16 * nb, 64);
#pragma unroll
          for (int i = 0; i < 4; ++i)
            Pl[w][quad * 4 + i][l15 + 16 * nb] = f2bf_fast(exp2_hw(sfr[nb][i] * c2 + bb));
        }
      } else {                               // boundary tile: add causal mask
#pragma unroll
        for (int nb = 0; nb < 4; ++nb) {
          const int tg = l15 + 16 * nb;
          const float bb = __shfl(kbr, l15 + 16 * nb, 64);
#pragma unroll
          for (int i = 0; i < 4; ++i) {
            const float bbi = (tg > 16 * w + quad * 4 + i) ? -1.0e38f : bb;
            Pl[w][quad * 4 + i][l15 + 16 * nb] = f2bf_fast(exp2_hw(sfr[nb][i] * c2 + bbi));
          }
        }
      }
      asm volatile("s_waitcnt lgkmcnt(0)" ::: "memory");  // own-wave Pl writes
      bf16x8 ap0 = *(const bf16x8*)&Pl[w][l15][quad * 8];
      bf16x8 ap1 = *(const bf16x8*)&Pl[w][l15][32 + quad * 8];
#pragma unroll
      for (int no = 0; no < 4; ++no) {
        o[no] = __builtin_amdgcn_mfma_f32_16x16x32_bf16(ap0, bv[no][0], o[no], 0, 0, 0);
        o[no] = __builtin_amdgcn_mfma_f32_16x16x32_bf16(ap1, bv[no][1], o[no], 0, 0, 0);
      }
      lsum = __builtin_amdgcn_mfma_f32_16x16x32_bf16(ap0, ones, lsum, 0, 0, 0);
      lsum = __builtin_amdgcn_mfma_f32_16x16x32_bf16(ap1, ones, lsum, 0, 0, 0);
    }
    // epilogue: write partials; kh=0 also writes V rows for masked queries
    for (int i = 0; i < 4; ++i) {
      const int s = r0 + 16 * w + quad * 4 + i;
      const int qm = maskp[b * S_ + s];
      const size_t row = (size_t)(b * S_ + s) * E_ + hd * D_;
      if (kh == 0 && !qm) {
        for (int no = 0; no < 4; ++no) {
          const int d = l15 + 16 * no;
          ob[row + d] = vtb[(size_t)d * S_ + s];
        }
      }
      for (int no = 0; no < 4; ++no)
        PB[row + l15 + 16 * no] = f2bf(o[no][i]);
      if (l15 == 0)
        LB[bh * S_ + s] = lsum[i];
    }
  }
}

// ---------------------------------------------------------------------------
// merge: ob[m][e] = (P0 + P1) / (l0 + l1) for unmasked rows
// ---------------------------------------------------------------------------
__global__ __launch_bounds__(256) void merge_kernel(
    const short* __restrict__ pb0, const short* __restrict__ pb1,
    const float* __restrict__ lb0, const float* __restrict__ lb1,
    const int* __restrict__ maskp, short* __restrict__ ob) {
  int idx = blockIdx.x * 256 + threadIdx.x;  // 8192*64 threads
  int m = idx >> 6, e = (idx & 63) * 8;
  if (!maskp[m]) return;                     // masked row: flash wrote V
  int b = m >> 11, s = m & (S_ - 1);
  int bh = b * 8 + (e >> 6);
  float l = lb0[bh * S_ + s] + lb1[bh * S_ + s];
  float inv = 1.f / l;
  bf16x8 p0 = *(const bf16x8*)&pb0[(size_t)m * E_ + e];
  bf16x8 p1 = *(const bf16x8*)&pb1[(size_t)m * E_ + e];
  bf16x8 r;
  for (int j = 0; j < 8; ++j)
    r[j] = f2bf((bf2f(p0[j]) + bf2f(p1[j])) * inv);
  *(bf16x8*)&ob[(size_t)m * E_ + e] = r;
}

extern "C" void kernel_launch(void* const* d_in, const int* in_sizes, int n_in,
                              void* d_out, int out_size, void* d_ws, size_t ws_size,
                              hipStream_t stream) {
  const float* x    = (const float*)d_in[0];
  const int*   mask = (const int*)d_in[1];
  const float* Win  = (const float*)d_in[2];
  const float* Wout = (const float*)d_in[3];
  float* out = (float*)d_out;

  short* Xb    = (short*)d_ws;               // 8192*512
  short* Winb  = Xb + 8192 * 512;            // 1536*512
  short* Woutb = Winb + 1536 * 512;          // 512*512
  short* qb    = Woutb + 512 * 512;          // 32*2048*64 each
  short* kb    = qb + 32 * 2048 * 64;
  short* vbT   = kb + 32 * 2048 * 64;        // [bh][d][s] transposed
  short* ob    = vbT + 32 * 2048 * 64;       // 8192*512
  short* pb0   = ob + 8192 * 512;            // partial O, half 0 (bf16)
  short* pb1   = pb0 + 8192 * 512;           // partial O, half 1
  float* lb0   = (float*)(pb1 + 8192 * 512); // lsum partials [32][2048]
  float* lb1   = lb0 + 32 * 2048;            // total ws ~61.3 MB

  cvt_all<<<5120, 256, 0, stream>>>(x, Win, Wout, Xb, Winb, Woutb);
  gemm_qkv_mfma<<<dim3(64, 24), 256, 0, stream>>>(Xb, Winb, qb, kb, vbT);
  flash_mfma<<<1024, 256, 0, stream>>>(qb, kb, vbT, mask, pb0, pb1, lb0, lb1, ob);
  merge_kernel<<<2048, 256, 0, stream>>>(pb0, pb1, lb0, lb1, mask, ob);
  gemm_out_mfma<<<dim3(64, 8), 256, 0, stream>>>(ob, Woutb, out);
}

// Round 6
// 162.065 us; speedup vs baseline: 1.5390x; 1.5390x over previous
//
#include <hip/hip_runtime.h>
#include <math.h>

// Problem constants
#define B_ 4
#define S_ 2048
#define E_ 512
#define H_ 8
#define D_ 64

typedef short bf16x8 __attribute__((ext_vector_type(8)));
typedef float f32x4 __attribute__((ext_vector_type(4)));

__device__ inline short f2bf(float f) {  // fp32 -> bf16 bits, RNE
  union { float f; unsigned u; } v; v.f = f;
  unsigned r = v.u + 0x7FFF + ((v.u >> 16) & 1);
  return (short)(r >> 16);
}
__device__ inline short f2bf_fast(float f) {  // round-half-up (P matrix only)
  union { float f; unsigned u; } v; v.f = f;
  return (short)((v.u + 0x8000u) >> 16);
}
__device__ inline float bf2f(short s) {
  union { unsigned u; float f; } v; v.u = ((unsigned)(unsigned short)s) << 16;
  return v.f;
}
// raw v_exp_f32: 2^x in one instruction (libm exp2f is ~10 instrs of
// edge-case scaffolding; inputs finite, very-negative -> 0 is the desired
// mask behavior). Correctness verified in r5 (same absmax incl. mask path).
__device__ __forceinline__ float exp2_hw(float x) {
  float r; asm("v_exp_f32 %0, %1" : "=v"(r) : "v"(x)); return r;
}

// Async global->LDS, 16B per lane. HW writes wave-uniform LDS base + lane*16;
// every wave's per-lane pointers here are exactly base+lane*16 (flat unpadded
// layout, slot = tid*16B; uniform buffer offset preserves the property).
__device__ __forceinline__ void gload16(const short* g, short* l) {
  __builtin_amdgcn_global_load_lds(
      (__attribute__((address_space(1))) void*)g,
      (__attribute__((address_space(3))) void*)l, 16, 0, 0);
}

// ---------------------------------------------------------------------------
// fused fp32->bf16 convert for X, W_in, W_out in ONE launch (block ranges)
// ---------------------------------------------------------------------------
__global__ __launch_bounds__(256) void cvt_all(
    const float* __restrict__ x, const float* __restrict__ win,
    const float* __restrict__ wout, short* __restrict__ xb,
    short* __restrict__ winb, short* __restrict__ woutb) {
  int bid = blockIdx.x;
  const float* src; short* dst; int i;
  if (bid < 4096)      { src = x;    dst = xb;    i = bid * 256 + threadIdx.x; }
  else if (bid < 4864) { src = win;  dst = winb;  i = (bid - 4096) * 256 + threadIdx.x; }
  else                 { src = wout; dst = woutb; i = (bid - 4864) * 256 + threadIdx.x; }
  float4 f = ((const float4*)src)[i];
  short4 o;
  o.x = f2bf(f.x); o.y = f2bf(f.y); o.z = f2bf(f.z); o.w = f2bf(f.w);
  ((short4*)dst)[i] = o;
}

// ---------------------------------------------------------------------------
// MFMA GEMM qkv (r4 structure, proven): 128x64 tile, BK=32, 4 waves,
// async global_load_lds staging, LDS dbuf, ONE barrier/K-step, 1536 blocks
// = 6/CU. Epilogue fuses RoPE; q,k [bh][s][d]; V TRANSPOSED [bh][d][s].
// ---------------------------------------------------------------------------
__global__ __launch_bounds__(256, 6) void gemm_qkv_mfma(
    const short* __restrict__ Xb,    // [8192][512] bf16
    const short* __restrict__ Wb,    // [1536][512] bf16
    short* __restrict__ qb, short* __restrict__ kb, short* __restrict__ vbT) {
  __shared__ __align__(16) short As[2 * 128 * 32];   // 16 KB
  __shared__ __align__(16) short Bs[2 * 64 * 32];    //  8 KB
  const int tid = threadIdx.x;
  const int w = tid >> 6, lane = tid & 63;
  const int l15 = lane & 15, quad = lane >> 4;
  const int wm = w & 1, wn = w >> 1;
  const int m0 = blockIdx.x * 128;
  const int n0 = blockIdx.y * 64;

  const int srow = tid >> 2, sch = (tid & 3) * 8;
  const short* gA0 = Xb + (size_t)(m0 + srow) * E_ + sch;
  const short* gA1 = Xb + (size_t)(m0 + srow + 64) * E_ + sch;
  const short* gB0 = Wb + (size_t)(n0 + srow) * E_ + sch;

  f32x4 acc[4][2];
  for (int mt = 0; mt < 4; ++mt)
    for (int nt = 0; nt < 2; ++nt) acc[mt][nt] = (f32x4){0.f, 0.f, 0.f, 0.f};

  gload16(gA0, &As[tid * 8]);
  gload16(gA1, &As[2048 + tid * 8]);
  gload16(gB0, &Bs[tid * 8]);
  gA0 += 32; gA1 += 32; gB0 += 32;
  __syncthreads();

  int cur = 0;
  for (int t = 0; t < 16; ++t) {
    if (t < 15) {
      const int nbA = (cur ^ 1) * 4096, nbB = (cur ^ 1) * 2048;
      gload16(gA0, &As[nbA + tid * 8]);
      gload16(gA1, &As[nbA + 2048 + tid * 8]);
      gload16(gB0, &Bs[nbB + tid * 8]);
      gA0 += 32; gA1 += 32; gB0 += 32;
    }
    const int cbA = cur * 4096, cbB = cur * 2048;
    bf16x8 a[4], bfr[2];
#pragma unroll
    for (int mt = 0; mt < 4; ++mt)
      a[mt] = *(const bf16x8*)&As[cbA + (wm * 64 + mt * 16 + l15) * 32 + quad * 8];
#pragma unroll
    for (int nt = 0; nt < 2; ++nt)
      bfr[nt] = *(const bf16x8*)&Bs[cbB + (wn * 32 + nt * 16 + l15) * 32 + quad * 8];
#pragma unroll
    for (int mt = 0; mt < 4; ++mt)
#pragma unroll
      for (int nt = 0; nt < 2; ++nt)
        acc[mt][nt] = __builtin_amdgcn_mfma_f32_16x16x32_bf16(a[mt], bfr[nt], acc[mt][nt], 0, 0, 0);
    __syncthreads();
    cur ^= 1;
  }

  const int t3 = n0 >> 9;                // uniform per block: 0=q 1=k 2=v
  for (int nt = 0; nt < 2; ++nt) {
    const int n = n0 + wn * 32 + nt * 16 + l15;
    const int h = (n >> 6) & 7;
    const int d = n & 63;
    const bool dorope = (t3 < 2) && (d < 32);
    const float sgn = (d & 1) ? 1.f : -1.f;
    const float fr = dorope ? exp2f((float)(d >> 1) * -0.8304820237f) : 0.f;
    for (int mt = 0; mt < 4; ++mt) {
      for (int i = 0; i < 4; ++i) {
        const int m = m0 + wm * 64 + mt * 16 + quad * 4 + i;
        const int b = m >> 11, s = m & (S_ - 1);
        float val = acc[mt][nt][i];
        float pv = __shfl_xor(val, 1, 64);
        float outv = val;
        if (dorope) {
          float ang = (float)s * fr;
          float sn, cs;
          sincosf(ang, &sn, &cs);
          outv = val * cs + pv * sgn * sn;
        }
        if (t3 == 2)
          vbT[((size_t)(b * 8 + h) * D_ + d) * S_ + s] = f2bf(outv);
        else {
          short* dst = (t3 == 0) ? qb : kb;
          dst[(((size_t)(b * 8 + h)) * S_ + s) * D_ + d] = f2bf(outv);
        }
      }
    }
  }
}

// ---------------------------------------------------------------------------
// gemm_out: out = ob @ Woutb^T, fp32 output (r4 structure, proven).
// ---------------------------------------------------------------------------
__global__ __launch_bounds__(256) void gemm_out_mfma(
    const short* __restrict__ Ab, const short* __restrict__ Wb,
    float* __restrict__ out) {
  __shared__ __align__(16) short As[2 * 128 * 32];
  __shared__ __align__(16) short Bs[2 * 64 * 32];
  const int tid = threadIdx.x;
  const int w = tid >> 6, lane = tid & 63;
  const int l15 = lane & 15, quad = lane >> 4;
  const int wm = w & 1, wn = w >> 1;
  const int m0 = blockIdx.x * 128;
  const int n0 = blockIdx.y * 64;

  const int srow = tid >> 2, sch = (tid & 3) * 8;
  const short* gA0 = Ab + (size_t)(m0 + srow) * E_ + sch;
  const short* gA1 = Ab + (size_t)(m0 + srow + 64) * E_ + sch;
  const short* gB0 = Wb + (size_t)(n0 + srow) * E_ + sch;

  f32x4 acc[4][2];
  for (int mt = 0; mt < 4; ++mt)
    for (int nt = 0; nt < 2; ++nt) acc[mt][nt] = (f32x4){0.f, 0.f, 0.f, 0.f};

  gload16(gA0, &As[tid * 8]);
  gload16(gA1, &As[2048 + tid * 8]);
  gload16(gB0, &Bs[tid * 8]);
  gA0 += 32; gA1 += 32; gB0 += 32;
  __syncthreads();

  int cur = 0;
  for (int t = 0; t < 16; ++t) {
    if (t < 15) {
      const int nbA = (cur ^ 1) * 4096, nbB = (cur ^ 1) * 2048;
      gload16(gA0, &As[nbA + tid * 8]);
      gload16(gA1, &As[nbA + 2048 + tid * 8]);
      gload16(gB0, &Bs[nbB + tid * 8]);
      gA0 += 32; gA1 += 32; gB0 += 32;
    }
    const int cbA = cur * 4096, cbB = cur * 2048;
    bf16x8 a[4], bfr[2];
#pragma unroll
    for (int mt = 0; mt < 4; ++mt)
      a[mt] = *(const bf16x8*)&As[cbA + (wm * 64 + mt * 16 + l15) * 32 + quad * 8];
#pragma unroll
    for (int nt = 0; nt < 2; ++nt)
      bfr[nt] = *(const bf16x8*)&Bs[cbB + (wn * 32 + nt * 16 + l15) * 32 + quad * 8];
#pragma unroll
    for (int mt = 0; mt < 4; ++mt)
#pragma unroll
      for (int nt = 0; nt < 2; ++nt)
        acc[mt][nt] = __builtin_amdgcn_mfma_f32_16x16x32_bf16(a[mt], bfr[nt], acc[mt][nt], 0, 0, 0);
    __syncthreads();
    cur ^= 1;
  }
  for (int mt = 0; mt < 4; ++mt)
    for (int nt = 0; nt < 2; ++nt) {
      const int n = n0 + wn * 32 + nt * 16 + l15;
      for (int i = 0; i < 4; ++i) {
        const int m = m0 + wm * 64 + mt * 16 + quad * 4 + i;
        out[(size_t)m * E_ + n] = acc[mt][nt][i];
      }
    }
}

// ---------------------------------------------------------------------------
// Flash attention r6 = r4 structure (proven 51us: LDS-staged K/V, kbias LDS,
// 2 barriers/tile) + exp2_hw substitution (the one r5 change that survived
// the post-mortem; verified correct in r5).
// r5 post-mortem: direct-from-global fragments were 2.6x WORSE (134us,
// VALUBusy 9.5% = load-latency-bound). V fragment lanes sit at 4KB stride
// (l15*S_) -> 16 cache lines per 16-lane load, no coalescing; the LDS
// staging IS the coalescing step. Lesson #7 only applies when the direct
// read pattern is itself coalescible. DO NOT remove staging again.
// ---------------------------------------------------------------------------
__global__ __launch_bounds__(256) void flash_mfma(
    const short* __restrict__ qb, const short* __restrict__ kb,
    const short* __restrict__ vbT, const int* __restrict__ maskp,
    short* __restrict__ pb0, short* __restrict__ pb1,
    float* __restrict__ lb0, float* __restrict__ lb1,
    short* __restrict__ ob) {
  __shared__ __align__(16) short Ks[64][72];
  __shared__ __align__(16) short VT[64][72];
  __shared__ __align__(16) short Pl[4][16][72];
  __shared__ float kbias[64];
  const int tid = threadIdx.x;
  const int w = tid >> 6, lane = tid & 63;
  const int l15 = lane & 15, quad = lane >> 4;
  const int bid = blockIdx.x;
  const int u = bid & 7, v = bid >> 3;       // u -> XCD under id&7 model
  const int bh = (u << 2) | (v & 3);         // 4 bh per XCD
  const int w2 = v >> 2;                     // 0..31
  const int pair = w2 & 15;                  // q-tile pair id
  const int kh = w2 >> 4;                    // split half: 0 or 1
  const int b = bh >> 3, hd = bh & 7;
  const short* qbase = qb + (size_t)bh * S_ * D_;
  const short* kbase = kb + (size_t)bh * S_ * D_;
  const short* vtb   = vbT + (size_t)bh * D_ * S_;
  short* PB = kh ? pb1 : pb0;
  float* LB = kh ? lb1 : lb0;
  const float c2 = 0.1803368801f;            // 0.125 * log2(e)
  bf16x8 ones;
  for (int j = 0; j < 8; ++j) ones[j] = (short)0x3F80;  // bf16 1.0

  for (int seg = 0; seg < 2; ++seg) {
    const int qt = (seg == 0) ? pair : 31 - pair;
    const int r0 = qt * 64;
    const int mid = (qt + 2) >> 1;           // ceil((qt+1)/2)
    const int lo = kh ? mid : 0;
    const int hi = kh ? (qt + 1) : mid;
    bf16x8 aq[2];
    {
      const short* qrow = qbase + (size_t)(r0 + 16 * w + l15) * D_;
      aq[0] = *(const bf16x8*)&qrow[quad * 8];
      aq[1] = *(const bf16x8*)&qrow[32 + quad * 8];
    }
    f32x4 o[4], lsum;
    for (int no = 0; no < 4; ++no) o[no] = (f32x4){0.f, 0.f, 0.f, 0.f};
    lsum = (f32x4){0.f, 0.f, 0.f, 0.f};

    for (int kt = lo; kt < hi; ++kt) {
      const int t0 = kt * 64;
      __syncthreads();                       // prior tile fully consumed
      for (int l = 0; l < 2; ++l) {
        int idx = tid + 256 * l;
        int row = idx >> 3, ch = (idx & 7) * 8;
        *(bf16x8*)&Ks[row][ch] = *(const bf16x8*)(kbase + (size_t)(t0 + row) * D_ + ch);
        *(bf16x8*)&VT[row][ch] = *(const bf16x8*)(vtb + (size_t)row * S_ + t0 + ch);
      }
      if (tid < 64)
        kbias[tid] = maskp[b * S_ + t0 + tid] ? -23.08312f : -1.0e38f;
      __syncthreads();
      f32x4 sfr[4];
      for (int nb = 0; nb < 4; ++nb) sfr[nb] = (f32x4){0.f, 0.f, 0.f, 0.f};
      for (int nb = 0; nb < 4; ++nb)
        for (int ks = 0; ks < 2; ++ks) {
          bf16x8 bk = *(const bf16x8*)&Ks[l15 + 16 * nb][32 * ks + quad * 8];
          sfr[nb] = __builtin_amdgcn_mfma_f32_16x16x32_bf16(aq[ks], bk, sfr[nb], 0, 0, 0);
        }
      if (kt < qt) {                         // interior tiles: no causal test
        for (int nb = 0; nb < 4; ++nb) {
          const float bb = kbias[l15 + 16 * nb];
          for (int i = 0; i < 4; ++i)
            Pl[w][quad * 4 + i][l15 + 16 * nb] = f2bf_fast(exp2_hw(sfr[nb][i] * c2 + bb));
        }
      } else {                               // boundary tile: add causal mask
        for (int nb = 0; nb < 4; ++nb) {
          const int tg = l15 + 16 * nb;
          const float bb = kbias[l15 + 16 * nb];
          for (int i = 0; i < 4; ++i) {
            const float bbi = (tg > 16 * w + quad * 4 + i) ? -1.0e38f : bb;
            Pl[w][quad * 4 + i][l15 + 16 * nb] = f2bf_fast(exp2_hw(sfr[nb][i] * c2 + bbi));
          }
        }
      }
      asm volatile("s_waitcnt lgkmcnt(0)" ::: "memory");  // own-wave Pl writes
      bf16x8 ap0 = *(const bf16x8*)&Pl[w][l15][quad * 8];
      bf16x8 ap1 = *(const bf16x8*)&Pl[w][l15][32 + quad * 8];
      for (int no = 0; no < 4; ++no) {
        bf16x8 bv0 = *(const bf16x8*)&VT[16 * no + l15][quad * 8];
        bf16x8 bv1 = *(const bf16x8*)&VT[16 * no + l15][32 + quad * 8];
        o[no] = __builtin_amdgcn_mfma_f32_16x16x32_bf16(ap0, bv0, o[no], 0, 0, 0);
        o[no] = __builtin_amdgcn_mfma_f32_16x16x32_bf16(ap1, bv1, o[no], 0, 0, 0);
      }
      lsum = __builtin_amdgcn_mfma_f32_16x16x32_bf16(ap0, ones, lsum, 0, 0, 0);
      lsum = __builtin_amdgcn_mfma_f32_16x16x32_bf16(ap1, ones, lsum, 0, 0, 0);
    }
    // epilogue: write partials; kh=0 also writes V rows for masked queries
    for (int i = 0; i < 4; ++i) {
      const int s = r0 + 16 * w + quad * 4 + i;
      const int qm = maskp[b * S_ + s];
      const size_t row = (size_t)(b * S_ + s) * E_ + hd * D_;
      if (kh == 0 && !qm) {
        for (int no = 0; no < 4; ++no) {
          const int d = l15 + 16 * no;
          ob[row + d] = vtb[(size_t)d * S_ + s];
        }
      }
      for (int no = 0; no < 4; ++no)
        PB[row + l15 + 16 * no] = f2bf(o[no][i]);
      if (l15 == 0)
        LB[bh * S_ + s] = lsum[i];
    }
  }
}

// ---------------------------------------------------------------------------
// merge: ob[m][e] = (P0 + P1) / (l0 + l1) for unmasked rows
// ---------------------------------------------------------------------------
__global__ __launch_bounds__(256) void merge_kernel(
    const short* __restrict__ pb0, const short* __restrict__ pb1,
    const float* __restrict__ lb0, const float* __restrict__ lb1,
    const int* __restrict__ maskp, short* __restrict__ ob) {
  int idx = blockIdx.x * 256 + threadIdx.x;  // 8192*64 threads
  int m = idx >> 6, e = (idx & 63) * 8;
  if (!maskp[m]) return;                     // masked row: flash wrote V
  int b = m >> 11, s = m & (S_ - 1);
  int bh = b * 8 + (e >> 6);
  float l = lb0[bh * S_ + s] + lb1[bh * S_ + s];
  float inv = 1.f / l;
  bf16x8 p0 = *(const bf16x8*)&pb0[(size_t)m * E_ + e];
  bf16x8 p1 = *(const bf16x8*)&pb1[(size_t)m * E_ + e];
  bf16x8 r;
  for (int j = 0; j < 8; ++j)
    r[j] = f2bf((bf2f(p0[j]) + bf2f(p1[j])) * inv);
  *(bf16x8*)&ob[(size_t)m * E_ + e] = r;
}

extern "C" void kernel_launch(void* const* d_in, const int* in_sizes, int n_in,
                              void* d_out, int out_size, void* d_ws, size_t ws_size,
                              hipStream_t stream) {
  const float* x    = (const float*)d_in[0];
  const int*   mask = (const int*)d_in[1];
  const float* Win  = (const float*)d_in[2];
  const float* Wout = (const float*)d_in[3];
  float* out = (float*)d_out;

  short* Xb    = (short*)d_ws;               // 8192*512
  short* Winb  = Xb + 8192 * 512;            // 1536*512
  short* Woutb = Winb + 1536 * 512;          // 512*512
  short* qb    = Woutb + 512 * 512;          // 32*2048*64 each
  short* kb    = qb + 32 * 2048 * 64;
  short* vbT   = kb + 32 * 2048 * 64;        // [bh][d][s] transposed
  short* ob    = vbT + 32 * 2048 * 64;       // 8192*512
  short* pb0   = ob + 8192 * 512;            // partial O, half 0 (bf16)
  short* pb1   = pb0 + 8192 * 512;           // partial O, half 1
  float* lb0   = (float*)(pb1 + 8192 * 512); // lsum partials [32][2048]
  float* lb1   = lb0 + 32 * 2048;            // total ws ~61.3 MB

  cvt_all<<<5120, 256, 0, stream>>>(x, Win, Wout, Xb, Winb, Woutb);
  gemm_qkv_mfma<<<dim3(64, 24), 256, 0, stream>>>(Xb, Winb, qb, kb, vbT);
  flash_mfma<<<1024, 256, 0, stream>>>(qb, kb, vbT, mask, pb0, pb1, lb0, lb1, ob);
  merge_kernel<<<2048, 256, 0, stream>>>(pb0, pb1, lb0, lb1, mask, ob);
  gemm_out_mfma<<<dim3(64, 8), 256, 0, stream>>>(ob, Woutb, out);
}